// Round 3
// baseline (407.343 us; speedup 1.0000x reference)
//
#include <hip/hip_runtime.h>
#include <stdint.h>

typedef __bf16 v8bf __attribute__((ext_vector_type(8)));
typedef float  v4f  __attribute__((ext_vector_type(4)));

// 0.125 (1/sqrt(64)) * log2(e): folded into Q so attention uses exp2 directly.
#define QSCALE 0.18033688011112042f

// Async global -> LDS DMA, 16 B/lane; LDS base wave-uniform, lane*16 scatter.
typedef __attribute__((address_space(3))) void lds_vp;
typedef const __attribute__((address_space(1))) void gbl_vp;
__device__ __forceinline__ void gl_lds16(const __bf16* g, __bf16* l) {
    __builtin_amdgcn_global_load_lds((gbl_vp*)g, (lds_vp*)l, 16, 0, 0);
}

__device__ __forceinline__ v8bf cvt8(const float* __restrict__ p) {
    float4 x = *reinterpret_cast<const float4*>(p);
    float4 y = *reinterpret_cast<const float4*>(p + 4);
    v8bf r;
    r[0] = (__bf16)x.x; r[1] = (__bf16)x.y; r[2] = (__bf16)x.z; r[3] = (__bf16)x.w;
    r[4] = (__bf16)y.x; r[5] = (__bf16)y.y; r[6] = (__bf16)y.z; r[7] = (__bf16)y.w;
    return r;
}

// 4 weight matrices (1024x1024 f32 -> bf16), grid (512,4).
__global__ __launch_bounds__(256) void cvt_w(
    const float* __restrict__ w0, const float* __restrict__ w1,
    const float* __restrict__ w2, const float* __restrict__ w3,
    __bf16* __restrict__ o0, __bf16* __restrict__ o1,
    __bf16* __restrict__ o2, __bf16* __restrict__ o3)
{
    const float* src; __bf16* dst;
    switch (blockIdx.y) {
        case 0: src = w0; dst = o0; break;
        case 1: src = w1; dst = o1; break;
        case 2: src = w2; dst = o2; break;
        default: src = w3; dst = o3; break;
    }
    size_t i = ((size_t)blockIdx.x * 256 + threadIdx.x) * 8;
    *reinterpret_cast<v8bf*>(dst + i) = cvt8(src + i);
}

// 3 activation inputs (4096x1024 f32 -> bf16), grid (2048,3).
__global__ __launch_bounds__(256) void cvt_in(
    const float* __restrict__ i0, const float* __restrict__ i1,
    const float* __restrict__ i2,
    __bf16* __restrict__ o0, __bf16* __restrict__ o1, __bf16* __restrict__ o2)
{
    const float* src; __bf16* dst;
    switch (blockIdx.y) {
        case 0: src = i0; dst = o0; break;
        case 1: src = i1; dst = o1; break;
        default: src = i2; dst = o2; break;
    }
    size_t i = ((size_t)blockIdx.x * 256 + threadIdx.x) * 8;
    *reinterpret_cast<v8bf*>(dst + i) = cvt8(src + i);
}

// Double-buffered DMA GEMM. Tile 128m x 64n, BK=64, 4 waves (wave: 64m x 32n).
// Pipeline: [stage kb+1 into buf^1 via global_load_lds] while [compute buf];
// ONE barrier per iter covers both DMA completion and read/write hazards.
// XOR chunk swizzle: global chunk c of row r lands at LDS slot c^(r&7)
// -> fragment ds_read_b128 <=2-way bank-aliased (free per m136).
// mode 0: out bf16 [((b*16+h)*2048+n)*64+d]; mode 1: out bf16 [((b*16+h)*64+d)*2048+n];
// mode 2: out f32 [m*1024+nc].
__device__ __forceinline__ void gemm_body(
    const __bf16* __restrict__ A, const __bf16* __restrict__ W,
    const float* __restrict__ bias, void* __restrict__ outp,
    int mode, float oscale, int bx, int by)
{
    constexpr int K = 1024, N = 1024;
    __shared__ __align__(16) __bf16 As[2][128 * 64];
    __shared__ __align__(16) __bf16 Bs[2][64 * 64];

    const int lane = threadIdx.x & 63;
    const int wave = threadIdx.x >> 6;
    const int quad = lane >> 4;
    const int l15  = lane & 15;
    const int m_base = bx * 128;
    const int n_base = by * 64;
    const int wm = (wave & 1) * 64;
    const int wn = (wave >> 1) * 32;

    // Staging coords: A 16KB -> 4 insts/wave; B 8KB -> 2 insts/wave.
    int arow[4], acol[4], brow[2], bcol[2];
    #pragma unroll
    for (int i = 0; i < 4; ++i) {
        int L = (i * 4 + wave) * 64 + lane;
        int r = L >> 3, s = L & 7;
        arow[i] = r; acol[i] = (s ^ (r & 7)) * 8;
    }
    #pragma unroll
    for (int i = 0; i < 2; ++i) {
        int L = (i * 4 + wave) * 64 + lane;
        int r = L >> 3, s = L & 7;
        brow[i] = r; bcol[i] = (s ^ (r & 7)) * 8;
    }

    v4f acc[4][2];
    #pragma unroll
    for (int f = 0; f < 4; ++f)
        #pragma unroll
        for (int g = 0; g < 2; ++g) { v4f z = {0.f,0.f,0.f,0.f}; acc[f][g] = z; }

    // Prologue: stage kb=0 into buf 0.
    #pragma unroll
    for (int i = 0; i < 4; ++i)
        gl_lds16(A + (size_t)(m_base + arow[i]) * K + acol[i],
                 &As[0][(i * 4 + wave) * 512]);
    #pragma unroll
    for (int i = 0; i < 2; ++i)
        gl_lds16(W + (size_t)(n_base + brow[i]) * K + bcol[i],
                 &Bs[0][(i * 4 + wave) * 512]);
    __syncthreads();

    for (int it = 0; it < 16; ++it) {
        const int cur = it & 1, nxt = cur ^ 1;
        const int kn = ((it + 1) & 15) * 64;   // wraps on last iter (wasted DMA)
        #pragma unroll
        for (int i = 0; i < 4; ++i)
            gl_lds16(A + (size_t)(m_base + arow[i]) * K + kn + acol[i],
                     &As[nxt][(i * 4 + wave) * 512]);
        #pragma unroll
        for (int i = 0; i < 2; ++i)
            gl_lds16(W + (size_t)(n_base + brow[i]) * K + kn + bcol[i],
                     &Bs[nxt][(i * 4 + wave) * 512]);

        #pragma unroll
        for (int ks = 0; ks < 2; ++ks) {
            v8bf af[4], bf[2];
            #pragma unroll
            for (int f = 0; f < 4; ++f) {
                const int R = wm + f * 16 + l15;
                const int slot = (ks * 4 + quad) ^ (R & 7);
                af[f] = *reinterpret_cast<const v8bf*>(&As[cur][R * 64 + slot * 8]);
            }
            #pragma unroll
            for (int g = 0; g < 2; ++g) {
                const int R = wn + g * 16 + l15;
                const int slot = (ks * 4 + quad) ^ (R & 7);
                bf[g] = *reinterpret_cast<const v8bf*>(&Bs[cur][R * 64 + slot * 8]);
            }
            __builtin_amdgcn_s_setprio(1);
            #pragma unroll
            for (int f = 0; f < 4; ++f)
                #pragma unroll
                for (int g = 0; g < 2; ++g)
                    acc[f][g] = __builtin_amdgcn_mfma_f32_16x16x32_bf16(
                        af[f], bf[g], acc[f][g], 0, 0, 0);
            __builtin_amdgcn_s_setprio(0);
        }
        __syncthreads();   // DMA for it+1 done + all reads of cur done
    }

    #pragma unroll
    for (int f = 0; f < 4; ++f)
        #pragma unroll
        for (int g = 0; g < 2; ++g) {
            const int nc = n_base + wn + g * 16 + l15;
            const float bval = bias[nc];
            #pragma unroll
            for (int r = 0; r < 4; ++r) {
                const int m = m_base + wm + f * 16 + quad * 4 + r;
                const float v = (acc[f][g][r] + bval) * oscale;
                if (mode == 2) {
                    ((float*)outp)[(size_t)m * N + nc] = v;
                } else {
                    int b = m >> 11, n = m & 2047, h = nc >> 6, d = nc & 63;
                    size_t off = (mode == 0)
                        ? ((size_t)(b * 16 + h) * 2048 + n) * 64 + d
                        : ((size_t)(b * 16 + h) * 64 + d) * 2048 + n;
                    ((__bf16*)outp)[off] = (__bf16)v;
                }
            }
        }
}

// Fused QKV projections. 1D grid 1536: id%16 = by (by%8 -> XCD-local W slice).
__global__ __launch_bounds__(256) void qkv_gemm(
    const __bf16* __restrict__ Aq, const __bf16* __restrict__ Ak,
    const __bf16* __restrict__ Av,
    const __bf16* __restrict__ Wq, const __bf16* __restrict__ Wk,
    const __bf16* __restrict__ Wv,
    const float* __restrict__ bq, const float* __restrict__ bk,
    const float* __restrict__ bv,
    __bf16* __restrict__ Qo, __bf16* __restrict__ Ko, __bf16* __restrict__ Vo)
{
    const int id = blockIdx.x;
    const int by = id & 15;
    const int bx = (id >> 4) & 31;
    const int z  = id >> 9;

    const __bf16 *A, *W; const float* bias; __bf16* outp; float oscale; int mode;
    switch (z) {
        case 0:  A = Aq; W = Wq; bias = bq; outp = Qo; oscale = QSCALE; mode = 0; break;
        case 1:  A = Ak; W = Wk; bias = bk; outp = Ko; oscale = 1.0f;   mode = 0; break;
        default: A = Av; W = Wv; bias = bv; outp = Vo; oscale = 1.0f;   mode = 1; break;
    }
    gemm_body(A, W, bias, outp, mode, oscale, bx, by);
}

// Final projection, f32 out. 1D grid 512: id%16 = by.
__global__ __launch_bounds__(256) void out_gemm(
    const __bf16* __restrict__ A, const __bf16* __restrict__ W,
    const float* __restrict__ bias, float* __restrict__ outp)
{
    const int by = blockIdx.x & 15;
    const int bx = blockIdx.x >> 4;
    gemm_body(A, W, bias, outp, 2, 1.0f, bx, by);
}

// Flash attention, fixed-shift softmax (no max subtraction).
// THIS ROUND: K/V are NOT staged in LDS. For one head K+V = 512KB and the
// id%8 XCD swizzle keeps the per-XCD working set at 4 heads x 512KB = 2MB,
// fully L2-resident (4MB/XCD) -- staging + per-kt barriers was pure overhead
// (Common-mistake #7 / m169). Fragments load straight from global into VGPRs:
// per b128 instruction, 16 rows x 64B contiguous -> clean L2 traffic.
// ZERO barriers: every wave runs fully independently (P buffer is
// wave-private). V loads issue before the softmax so their latency hides
// under QK MFMA + exp2.
// 8 waves x 16 q-rows (512 threads). 1D grid 512: id%8 = bh%8.
// Q,K: bf16 [b,h,2048,64]; V: bf16 [b,h,64,2048]; O: bf16 [4096,1024].
__global__ __launch_bounds__(512, 4) void attn_kernel(
    const __bf16* __restrict__ Q, const __bf16* __restrict__ Kb_,
    const __bf16* __restrict__ Vt, __bf16* __restrict__ O)
{
    __shared__ __align__(16) __bf16 p_lds[8][16][72];   // per-wave [q][k], +8 pad

    const int lane = threadIdx.x & 63;
    const int wave = threadIdx.x >> 6;   // 0..7, one 16-row strip each
    const int quad = lane >> 4;
    const int l15  = lane & 15;
    const int bh = blockIdx.x & 31;      // id%8 = bh%8 -> XCD locality
    const int qt = blockIdx.x >> 5;      // 0..15 (128-row q tiles)
    const int b  = bh >> 4, h = bh & 15;

    const __bf16* Qh = Q   + (size_t)bh * 2048 * 64;
    const __bf16* Kh = Kb_ + (size_t)bh * 2048 * 64;
    const __bf16* Vh = Vt  + (size_t)bh * 64 * 2048;

    v8bf qf[2];
    #pragma unroll
    for (int ks = 0; ks < 2; ++ks)
        qf[ks] = *reinterpret_cast<const v8bf*>(
            Qh + (size_t)(qt * 128 + wave * 16 + l15) * 64 + ks * 32 + quad * 8);

    v4f o_acc[4];
    #pragma unroll
    for (int c = 0; c < 4; ++c) { v4f z = {0.f,0.f,0.f,0.f}; o_acc[c] = z; }
    float l_r[4] = {0.f, 0.f, 0.f, 0.f};

    for (int kt = 0; kt < 32; ++kt) {
        // K fragments: row = key kt*64 + c*16 + l15, cols ks*32+quad*8 (+8).
        v8bf kf[2][4];
        #pragma unroll
        for (int ks = 0; ks < 2; ++ks)
            #pragma unroll
            for (int c = 0; c < 4; ++c)
                kf[ks][c] = *reinterpret_cast<const v8bf*>(
                    Kh + (size_t)(kt * 64 + c * 16 + l15) * 64 + ks * 32 + quad * 8);
        // V fragments (issued now; consumed after softmax -> latency hidden).
        // row = d (c*16+l15), col window kt*64 within [64][2048].
        v8bf vf[2][4];
        #pragma unroll
        for (int ks = 0; ks < 2; ++ks)
            #pragma unroll
            for (int c = 0; c < 4; ++c)
                vf[ks][c] = *reinterpret_cast<const v8bf*>(
                    Vh + (size_t)(c * 16 + l15) * 2048 + kt * 64 + ks * 32 + quad * 8);

        // S = Q @ K^T (scores in log2 domain via Q pre-scale).
        v4f s_t[4];
        #pragma unroll
        for (int c = 0; c < 4; ++c) { v4f z = {0.f,0.f,0.f,0.f}; s_t[c] = z; }
        #pragma unroll
        for (int ks = 0; ks < 2; ++ks) {
            __builtin_amdgcn_s_setprio(1);
            #pragma unroll
            for (int c = 0; c < 4; ++c)
                s_t[c] = __builtin_amdgcn_mfma_f32_16x16x32_bf16(qf[ks], kf[ks][c], s_t[c], 0, 0, 0);
            __builtin_amdgcn_s_setprio(0);
        }

        // p = 2^s; per-lane row-sum partials; stage P (wave-private, no barrier).
        // s_t[c][r] = S[q=quad*4+r][k=c*16+l15].
        #pragma unroll
        for (int r = 0; r < 4; ++r) {
            const float p0 = __builtin_exp2f(s_t[0][r]);
            const float p1 = __builtin_exp2f(s_t[1][r]);
            const float p2 = __builtin_exp2f(s_t[2][r]);
            const float p3 = __builtin_exp2f(s_t[3][r]);
            l_r[r] += (p0 + p1) + (p2 + p3);
            p_lds[wave][quad * 4 + r][0 * 16 + l15] = (__bf16)p0;
            p_lds[wave][quad * 4 + r][1 * 16 + l15] = (__bf16)p1;
            p_lds[wave][quad * 4 + r][2 * 16 + l15] = (__bf16)p2;
            p_lds[wave][quad * 4 + r][3 * 16 + l15] = (__bf16)p3;
        }

        // O += P @ V
        #pragma unroll
        for (int ks = 0; ks < 2; ++ks) {
            const v8bf pf = *reinterpret_cast<const v8bf*>(
                &p_lds[wave][l15][ks * 32 + quad * 8]);
            __builtin_amdgcn_s_setprio(1);
            #pragma unroll
            for (int c = 0; c < 4; ++c)
                o_acc[c] = __builtin_amdgcn_mfma_f32_16x16x32_bf16(pf, vf[ks][c], o_acc[c], 0, 0, 0);
            __builtin_amdgcn_s_setprio(0);
        }
    }

    // Reduce l across 16 lanes per row; write O bf16 [b*2048+q, h*64+d].
    #pragma unroll
    for (int r = 0; r < 4; ++r) {
        float l = l_r[r];
        #pragma unroll
        for (int off = 1; off < 16; off <<= 1)
            l += __shfl_xor(l, off, 16);
        const float inv_l = 1.0f / l;
        const int qr = qt * 128 + wave * 16 + quad * 4 + r;
        #pragma unroll
        for (int c = 0; c < 4; ++c) {
            const int col = h * 64 + c * 16 + l15;
            O[(size_t)(b * 2048 + qr) * 1024 + col] = (__bf16)(o_acc[c][r] * inv_l);
        }
    }
}

extern "C" void kernel_launch(void* const* d_in, const int* in_sizes, int n_in,
                              void* d_out, int out_size, void* d_ws, size_t ws_size,
                              hipStream_t stream) {
    const float* q_in = (const float*)d_in[0];
    const float* k_in = (const float*)d_in[1];
    const float* v_in = (const float*)d_in[2];
    const float* Wq = (const float*)d_in[3];
    const float* bq = (const float*)d_in[4];
    const float* Wk = (const float*)d_in[5];
    const float* bk = (const float*)d_in[6];
    const float* Wv = (const float*)d_in[7];
    const float* bv = (const float*)d_in[8];
    const float* Wo = (const float*)d_in[9];
    const float* bo = (const float*)d_in[10];
    float* out = (float*)d_out;

    // Workspace (bf16 elements), 56 MiB. Ob aliases Abq (consumed before attn).
    __bf16* ws  = (__bf16*)d_ws;
    __bf16* Abq = ws;                  // [4096,1024]
    __bf16* Abk = Abq + 4194304;
    __bf16* Abv = Abk + 4194304;
    __bf16* Qb  = Abv + 4194304;       // [2,16,2048,64]
    __bf16* Kb  = Qb  + 4194304;
    __bf16* Vb  = Kb  + 4194304;       // [2,16,64,2048]
    __bf16* Wqb = Vb  + 4194304;       // [1024,1024] x4
    __bf16* Wkb = Wqb + 1048576;
    __bf16* Wvb = Wkb + 1048576;
    __bf16* Wob = Wvb + 1048576;
    __bf16* Ob  = Abq;                 // alias

    cvt_w<<<dim3(512, 4), 256, 0, stream>>>(Wq, Wk, Wv, Wo, Wqb, Wkb, Wvb, Wob);
    cvt_in<<<dim3(2048, 3), 256, 0, stream>>>(q_in, k_in, v_in, Abq, Abk, Abv);

    qkv_gemm<<<1536, 256, 0, stream>>>(
        Abq, Abk, Abv, Wqb, Wkb, Wvb, bq, bk, bv, Qb, Kb, Vb);

    attn_kernel<<<512, 512, 0, stream>>>(Qb, Kb, Vb, Ob);

    out_gemm<<<512, 256, 0, stream>>>(Ob, Wob, bo, out);
}

// Round 4
// 246.034 us; speedup vs baseline: 1.6556x; 1.6556x over previous
//
#include <hip/hip_runtime.h>
#include <stdint.h>

typedef __bf16 v8bf __attribute__((ext_vector_type(8)));
typedef float  v4f  __attribute__((ext_vector_type(4)));

// 0.125 (1/sqrt(64)) * log2(e): folded into Q so attention uses exp2 directly.
#define QSCALE 0.18033688011112042f

// Async global -> LDS DMA, 16 B/lane; LDS base wave-uniform, lane*16 scatter.
typedef __attribute__((address_space(3))) void lds_vp;
typedef const __attribute__((address_space(1))) void gbl_vp;
__device__ __forceinline__ void gl_lds16(const __bf16* g, __bf16* l) {
    __builtin_amdgcn_global_load_lds((gbl_vp*)g, (lds_vp*)l, 16, 0, 0);
}

__device__ __forceinline__ v8bf cvt8(const float* __restrict__ p) {
    float4 x = *reinterpret_cast<const float4*>(p);
    float4 y = *reinterpret_cast<const float4*>(p + 4);
    v8bf r;
    r[0] = (__bf16)x.x; r[1] = (__bf16)x.y; r[2] = (__bf16)x.z; r[3] = (__bf16)x.w;
    r[4] = (__bf16)y.x; r[5] = (__bf16)y.y; r[6] = (__bf16)y.z; r[7] = (__bf16)y.w;
    return r;
}

// 4 weight matrices (1024x1024 f32 -> bf16), grid (512,4).
__global__ __launch_bounds__(256) void cvt_w(
    const float* __restrict__ w0, const float* __restrict__ w1,
    const float* __restrict__ w2, const float* __restrict__ w3,
    __bf16* __restrict__ o0, __bf16* __restrict__ o1,
    __bf16* __restrict__ o2, __bf16* __restrict__ o3)
{
    const float* src; __bf16* dst;
    switch (blockIdx.y) {
        case 0: src = w0; dst = o0; break;
        case 1: src = w1; dst = o1; break;
        case 2: src = w2; dst = o2; break;
        default: src = w3; dst = o3; break;
    }
    size_t i = ((size_t)blockIdx.x * 256 + threadIdx.x) * 8;
    *reinterpret_cast<v8bf*>(dst + i) = cvt8(src + i);
}

// 3 activation inputs (4096x1024 f32 -> bf16), grid (2048,3).
__global__ __launch_bounds__(256) void cvt_in(
    const float* __restrict__ i0, const float* __restrict__ i1,
    const float* __restrict__ i2,
    __bf16* __restrict__ o0, __bf16* __restrict__ o1, __bf16* __restrict__ o2)
{
    const float* src; __bf16* dst;
    switch (blockIdx.y) {
        case 0: src = i0; dst = o0; break;
        case 1: src = i1; dst = o1; break;
        default: src = i2; dst = o2; break;
    }
    size_t i = ((size_t)blockIdx.x * 256 + threadIdx.x) * 8;
    *reinterpret_cast<v8bf*>(dst + i) = cvt8(src + i);
}

// Double-buffered DMA GEMM. Tile 128m x 64n, BK=64, 4 waves (wave: 64m x 32n).
// Pipeline: [stage kb+1 into buf^1 via global_load_lds] while [compute buf];
// ONE barrier per iter covers both DMA completion and read/write hazards.
// XOR chunk swizzle: global chunk c of row r lands at LDS slot c^(r&7)
// -> fragment ds_read_b128 <=2-way bank-aliased (free per m136).
// mode 0: out bf16 [((b*16+h)*2048+n)*64+d]; mode 1: out bf16 [((b*16+h)*64+d)*2048+n];
// mode 2: out f32 [m*1024+nc].
__device__ __forceinline__ void gemm_body(
    const __bf16* __restrict__ A, const __bf16* __restrict__ W,
    const float* __restrict__ bias, void* __restrict__ outp,
    int mode, float oscale, int bx, int by)
{
    constexpr int K = 1024, N = 1024;
    __shared__ __align__(16) __bf16 As[2][128 * 64];
    __shared__ __align__(16) __bf16 Bs[2][64 * 64];

    const int lane = threadIdx.x & 63;
    const int wave = threadIdx.x >> 6;
    const int quad = lane >> 4;
    const int l15  = lane & 15;
    const int m_base = bx * 128;
    const int n_base = by * 64;
    const int wm = (wave & 1) * 64;
    const int wn = (wave >> 1) * 32;

    // Staging coords: A 16KB -> 4 insts/wave; B 8KB -> 2 insts/wave.
    int arow[4], acol[4], brow[2], bcol[2];
    #pragma unroll
    for (int i = 0; i < 4; ++i) {
        int L = (i * 4 + wave) * 64 + lane;
        int r = L >> 3, s = L & 7;
        arow[i] = r; acol[i] = (s ^ (r & 7)) * 8;
    }
    #pragma unroll
    for (int i = 0; i < 2; ++i) {
        int L = (i * 4 + wave) * 64 + lane;
        int r = L >> 3, s = L & 7;
        brow[i] = r; bcol[i] = (s ^ (r & 7)) * 8;
    }

    v4f acc[4][2];
    #pragma unroll
    for (int f = 0; f < 4; ++f)
        #pragma unroll
        for (int g = 0; g < 2; ++g) { v4f z = {0.f,0.f,0.f,0.f}; acc[f][g] = z; }

    // Prologue: stage kb=0 into buf 0.
    #pragma unroll
    for (int i = 0; i < 4; ++i)
        gl_lds16(A + (size_t)(m_base + arow[i]) * K + acol[i],
                 &As[0][(i * 4 + wave) * 512]);
    #pragma unroll
    for (int i = 0; i < 2; ++i)
        gl_lds16(W + (size_t)(n_base + brow[i]) * K + bcol[i],
                 &Bs[0][(i * 4 + wave) * 512]);
    __syncthreads();

    for (int it = 0; it < 16; ++it) {
        const int cur = it & 1, nxt = cur ^ 1;
        const int kn = ((it + 1) & 15) * 64;   // wraps on last iter (wasted DMA)
        #pragma unroll
        for (int i = 0; i < 4; ++i)
            gl_lds16(A + (size_t)(m_base + arow[i]) * K + kn + acol[i],
                     &As[nxt][(i * 4 + wave) * 512]);
        #pragma unroll
        for (int i = 0; i < 2; ++i)
            gl_lds16(W + (size_t)(n_base + brow[i]) * K + kn + bcol[i],
                     &Bs[nxt][(i * 4 + wave) * 512]);

        #pragma unroll
        for (int ks = 0; ks < 2; ++ks) {
            v8bf af[4], bf[2];
            #pragma unroll
            for (int f = 0; f < 4; ++f) {
                const int R = wm + f * 16 + l15;
                const int slot = (ks * 4 + quad) ^ (R & 7);
                af[f] = *reinterpret_cast<const v8bf*>(&As[cur][R * 64 + slot * 8]);
            }
            #pragma unroll
            for (int g = 0; g < 2; ++g) {
                const int R = wn + g * 16 + l15;
                const int slot = (ks * 4 + quad) ^ (R & 7);
                bf[g] = *reinterpret_cast<const v8bf*>(&Bs[cur][R * 64 + slot * 8]);
            }
            __builtin_amdgcn_s_setprio(1);
            #pragma unroll
            for (int f = 0; f < 4; ++f)
                #pragma unroll
                for (int g = 0; g < 2; ++g)
                    acc[f][g] = __builtin_amdgcn_mfma_f32_16x16x32_bf16(
                        af[f], bf[g], acc[f][g], 0, 0, 0);
            __builtin_amdgcn_s_setprio(0);
        }
        __syncthreads();   // DMA for it+1 done + all reads of cur done
    }

    #pragma unroll
    for (int f = 0; f < 4; ++f)
        #pragma unroll
        for (int g = 0; g < 2; ++g) {
            const int nc = n_base + wn + g * 16 + l15;
            const float bval = bias[nc];
            #pragma unroll
            for (int r = 0; r < 4; ++r) {
                const int m = m_base + wm + f * 16 + quad * 4 + r;
                const float v = (acc[f][g][r] + bval) * oscale;
                if (mode == 2) {
                    ((float*)outp)[(size_t)m * N + nc] = v;
                } else {
                    int b = m >> 11, n = m & 2047, h = nc >> 6, d = nc & 63;
                    size_t off = (mode == 0)
                        ? ((size_t)(b * 16 + h) * 2048 + n) * 64 + d
                        : ((size_t)(b * 16 + h) * 64 + d) * 2048 + n;
                    ((__bf16*)outp)[off] = (__bf16)v;
                }
            }
        }
}

// Fused QKV projections. 1D grid 1536: id%16 = by (by%8 -> XCD-local W slice).
__global__ __launch_bounds__(256) void qkv_gemm(
    const __bf16* __restrict__ Aq, const __bf16* __restrict__ Ak,
    const __bf16* __restrict__ Av,
    const __bf16* __restrict__ Wq, const __bf16* __restrict__ Wk,
    const __bf16* __restrict__ Wv,
    const float* __restrict__ bq, const float* __restrict__ bk,
    const float* __restrict__ bv,
    __bf16* __restrict__ Qo, __bf16* __restrict__ Ko, __bf16* __restrict__ Vo)
{
    const int id = blockIdx.x;
    const int by = id & 15;
    const int bx = (id >> 4) & 31;
    const int z  = id >> 9;

    const __bf16 *A, *W; const float* bias; __bf16* outp; float oscale; int mode;
    switch (z) {
        case 0:  A = Aq; W = Wq; bias = bq; outp = Qo; oscale = QSCALE; mode = 0; break;
        case 1:  A = Ak; W = Wk; bias = bk; outp = Ko; oscale = 1.0f;   mode = 0; break;
        default: A = Av; W = Wv; bias = bv; outp = Vo; oscale = 1.0f;   mode = 1; break;
    }
    gemm_body(A, W, bias, outp, mode, oscale, bx, by);
}

// Final projection, f32 out. 1D grid 512: id%16 = by.
__global__ __launch_bounds__(256) void out_gemm(
    const __bf16* __restrict__ A, const __bf16* __restrict__ W,
    const float* __restrict__ bias, float* __restrict__ outp)
{
    const int by = blockIdx.x & 15;
    const int bx = blockIdx.x >> 4;
    gemm_body(A, W, bias, outp, 2, 1.0f, bx, by);
}

// Flash attention, fixed-shift softmax (no max subtraction). R2 structure
// (LDS K/V staging, 8 waves x 16 q-rows, verified P path) with ONE change:
// TRIPLE-buffered K/V + counted vmcnt + raw s_barrier (T3/T4). Loads for
// kt+2 are issued at kt and stay in flight ACROSS the barrier; the wave
// waits only for the oldest 2 vmem ops (kt+1's K,V) via s_waitcnt vmcnt(2)
// -- never drains to 0 in the main loop (m218: the counted wait IS the
// pipeline gain; __syncthreads' vmcnt(0) drain was the per-kt stall).
// Cross-wave safety: each wave's own-slice DMA for kt+1 is complete before
// its barrier (vmcnt in-order retire), and reads of a buffer are consumed
// by MFMAs (lgkm waits) before the barrier that precedes its overwrite.
// 1D grid 512: id%8 = bh%8 (K/V XCD-local). Q,K: bf16 [b,h,2048,64];
// V: bf16 [b,h,64,2048]; O: bf16 [4096,1024].
__global__ __launch_bounds__(512, 4) void attn_kernel(
    const __bf16* __restrict__ Q, const __bf16* __restrict__ Kb_,
    const __bf16* __restrict__ Vt, __bf16* __restrict__ O)
{
    __shared__ __align__(16) __bf16 Ks[3][64 * 64];
    __shared__ __align__(16) __bf16 Vs[3][64 * 64];
    __shared__ __align__(16) __bf16 p_lds[8][16][72];   // per-wave [q][k], +8 pad

    const int lane = threadIdx.x & 63;
    const int wave = threadIdx.x >> 6;   // 0..7, one 16-row strip each
    const int quad = lane >> 4;
    const int l15  = lane & 15;
    const int bh = blockIdx.x & 31;      // id%8 = bh%8 -> XCD locality
    const int qt = blockIdx.x >> 5;      // 0..15 (128-row q tiles)
    const int b  = bh >> 4, h = bh & 15;

    const __bf16* Qh = Q   + (size_t)bh * 2048 * 64;
    const __bf16* Kh = Kb_ + (size_t)bh * 2048 * 64;
    const __bf16* Vh = Vt  + (size_t)bh * 64 * 2048;

    // Staging: one 16B DMA per lane for K and one for V (512 lanes = 8KB tile).
    const int L    = wave * 64 + lane;             // 0..511
    const int srow = L >> 3;                       // 0..63
    const int scol = ((L & 7) ^ (srow & 7)) * 8;   // pre-swizzled global chunk

    v8bf qf[2];
    #pragma unroll
    for (int ks = 0; ks < 2; ++ks)
        qf[ks] = *reinterpret_cast<const v8bf*>(
            Qh + (size_t)(qt * 128 + wave * 16 + l15) * 64 + ks * 32 + quad * 8);

    v4f o_acc[4];
    #pragma unroll
    for (int c = 0; c < 4; ++c) { v4f z = {0.f,0.f,0.f,0.f}; o_acc[c] = z; }
    float l_r[4] = {0.f, 0.f, 0.f, 0.f};

    // Prologue: stage kt=0 -> buf0, kt=1 -> buf1 (4 vmem ops in flight).
    gl_lds16(Kh + (size_t)srow * 64 + scol, &Ks[0][L * 8]);
    gl_lds16(Vh + (size_t)srow * 2048 + scol, &Vs[0][L * 8]);
    gl_lds16(Kh + (size_t)(64 + srow) * 64 + scol, &Ks[1][L * 8]);
    gl_lds16(Vh + (size_t)srow * 2048 + 64 + scol, &Vs[1][L * 8]);
    asm volatile("s_waitcnt vmcnt(2)" ::: "memory");   // kt=0's K,V landed
    __builtin_amdgcn_s_barrier();

    int cur = 0;
    for (int kt = 0; kt < 32; ++kt) {
        int pre = cur + 2; if (pre >= 3) pre -= 3;
        int ktn = kt + 2; if (ktn >= 32) ktn -= 32;   // wraps: wasted DMA, unread
        gl_lds16(Kh + (size_t)(ktn * 64 + srow) * 64 + scol, &Ks[pre][L * 8]);
        gl_lds16(Vh + (size_t)srow * 2048 + ktn * 64 + scol, &Vs[pre][L * 8]);

        // S = Q @ K^T (scores in log2 domain via Q pre-scale).
        v4f s_t[4];
        #pragma unroll
        for (int c = 0; c < 4; ++c) { v4f z = {0.f,0.f,0.f,0.f}; s_t[c] = z; }
        #pragma unroll
        for (int ks = 0; ks < 2; ++ks) {
            v8bf kf[4];
            #pragma unroll
            for (int c = 0; c < 4; ++c) {
                const int R = c * 16 + l15;
                const int slot = (ks * 4 + quad) ^ (R & 7);
                kf[c] = *reinterpret_cast<const v8bf*>(&Ks[cur][R * 64 + slot * 8]);
            }
            __builtin_amdgcn_s_setprio(1);
            #pragma unroll
            for (int c = 0; c < 4; ++c)
                s_t[c] = __builtin_amdgcn_mfma_f32_16x16x32_bf16(qf[ks], kf[c], s_t[c], 0, 0, 0);
            __builtin_amdgcn_s_setprio(0);
        }

        // p = 2^s; per-lane row-sum partials; stage P (wave-private, no barrier).
        // s_t[c][r] = S[q=quad*4+r][k=c*16+l15].
        #pragma unroll
        for (int r = 0; r < 4; ++r) {
            const float p0 = __builtin_exp2f(s_t[0][r]);
            const float p1 = __builtin_exp2f(s_t[1][r]);
            const float p2 = __builtin_exp2f(s_t[2][r]);
            const float p3 = __builtin_exp2f(s_t[3][r]);
            l_r[r] += (p0 + p1) + (p2 + p3);
            p_lds[wave][quad * 4 + r][0 * 16 + l15] = (__bf16)p0;
            p_lds[wave][quad * 4 + r][1 * 16 + l15] = (__bf16)p1;
            p_lds[wave][quad * 4 + r][2 * 16 + l15] = (__bf16)p2;
            p_lds[wave][quad * 4 + r][3 * 16 + l15] = (__bf16)p3;
        }

        // O += P @ V
        #pragma unroll
        for (int ks = 0; ks < 2; ++ks) {
            v8bf vf[4];
            #pragma unroll
            for (int c = 0; c < 4; ++c) {
                const int R = c * 16 + l15;
                const int slot = (ks * 4 + quad) ^ (R & 7);
                vf[c] = *reinterpret_cast<const v8bf*>(&Vs[cur][R * 64 + slot * 8]);
            }
            const v8bf pf = *reinterpret_cast<const v8bf*>(
                &p_lds[wave][l15][ks * 32 + quad * 8]);
            __builtin_amdgcn_s_setprio(1);
            #pragma unroll
            for (int c = 0; c < 4; ++c)
                o_acc[c] = __builtin_amdgcn_mfma_f32_16x16x32_bf16(pf, vf[c], o_acc[c], 0, 0, 0);
            __builtin_amdgcn_s_setprio(0);
        }

        // Counted wait: kt+1's 2 loads retired; kt+2's 2 may stay in flight.
        asm volatile("s_waitcnt vmcnt(2)" ::: "memory");
        __builtin_amdgcn_s_barrier();
        cur = (cur == 2) ? 0 : cur + 1;
    }

    // Reduce l across 16 lanes per row; write O bf16 [b*2048+q, h*64+d].
    #pragma unroll
    for (int r = 0; r < 4; ++r) {
        float l = l_r[r];
        #pragma unroll
        for (int off = 1; off < 16; off <<= 1)
            l += __shfl_xor(l, off, 16);
        const float inv_l = 1.0f / l;
        const int qr = qt * 128 + wave * 16 + quad * 4 + r;
        #pragma unroll
        for (int c = 0; c < 4; ++c) {
            const int col = h * 64 + c * 16 + l15;
            O[(size_t)(b * 2048 + qr) * 1024 + col] = (__bf16)(o_acc[c][r] * inv_l);
        }
    }
}

extern "C" void kernel_launch(void* const* d_in, const int* in_sizes, int n_in,
                              void* d_out, int out_size, void* d_ws, size_t ws_size,
                              hipStream_t stream) {
    const float* q_in = (const float*)d_in[0];
    const float* k_in = (const float*)d_in[1];
    const float* v_in = (const float*)d_in[2];
    const float* Wq = (const float*)d_in[3];
    const float* bq = (const float*)d_in[4];
    const float* Wk = (const float*)d_in[5];
    const float* bk = (const float*)d_in[6];
    const float* Wv = (const float*)d_in[7];
    const float* bv = (const float*)d_in[8];
    const float* Wo = (const float*)d_in[9];
    const float* bo = (const float*)d_in[10];
    float* out = (float*)d_out;

    // Workspace (bf16 elements), 56 MiB. Ob aliases Abq (consumed before attn).
    __bf16* ws  = (__bf16*)d_ws;
    __bf16* Abq = ws;                  // [4096,1024]
    __bf16* Abk = Abq + 4194304;
    __bf16* Abv = Abk + 4194304;
    __bf16* Qb  = Abv + 4194304;       // [2,16,2048,64]
    __bf16* Kb  = Qb  + 4194304;
    __bf16* Vb  = Kb  + 4194304;       // [2,16,64,2048]
    __bf16* Wqb = Vb  + 4194304;       // [1024,1024] x4
    __bf16* Wkb = Wqb + 1048576;
    __bf16* Wvb = Wkb + 1048576;
    __bf16* Wob = Wvb + 1048576;
    __bf16* Ob  = Abq;                 // alias

    cvt_w<<<dim3(512, 4), 256, 0, stream>>>(Wq, Wk, Wv, Wo, Wqb, Wkb, Wvb, Wob);
    cvt_in<<<dim3(2048, 3), 256, 0, stream>>>(q_in, k_in, v_in, Abq, Abk, Abv);

    qkv_gemm<<<1536, 256, 0, stream>>>(
        Abq, Abk, Abv, Wqb, Wkb, Wvb, bq, bk, bv, Qb, Kb, Vb);

    attn_kernel<<<512, 512, 0, stream>>>(Qb, Kb, Vb, Ob);

    out_gemm<<<512, 256, 0, stream>>>(Ob, Wob, bo, out);
}

// Round 5
// 245.053 us; speedup vs baseline: 1.6623x; 1.0040x over previous
//
#include <hip/hip_runtime.h>
#include <stdint.h>

typedef __bf16 v8bf __attribute__((ext_vector_type(8)));
typedef float  v4f  __attribute__((ext_vector_type(4)));
typedef float  v16f __attribute__((ext_vector_type(16)));
typedef unsigned int u32;
typedef unsigned int v4u __attribute__((ext_vector_type(4)));

// 0.125 (1/sqrt(64)) * log2(e): folded into Q so attention uses exp2 directly.
#define QSCALE 0.18033688011112042f

// Async global -> LDS DMA, 16 B/lane; LDS base wave-uniform, lane*16 scatter.
typedef __attribute__((address_space(3))) void lds_vp;
typedef const __attribute__((address_space(1))) void gbl_vp;
__device__ __forceinline__ void gl_lds16(const __bf16* g, __bf16* l) {
    __builtin_amdgcn_global_load_lds((gbl_vp*)g, (lds_vp*)l, 16, 0, 0);
}

// 2xf32 -> packed bf16 pair (no builtin on gfx950; RNE).
__device__ __forceinline__ u32 cvtpk(float a, float b) {
    u32 r;
    asm("v_cvt_pk_bf16_f32 %0, %1, %2" : "=v"(r) : "v"(a), "v"(b));
    return r;
}
// x.hi-lanes <-> y.lo-lanes (gfx950). After: x={x.lo | y.lo}, y={x.hi | y.hi}.
__device__ __forceinline__ void swapl(u32& x, u32& y) {
    asm("v_permlane32_swap_b32 %0, %1" : "+v"(x), "+v"(y));
}

__device__ __forceinline__ v8bf cvt8(const float* __restrict__ p) {
    float4 x = *reinterpret_cast<const float4*>(p);
    float4 y = *reinterpret_cast<const float4*>(p + 4);
    v8bf r;
    r[0] = (__bf16)x.x; r[1] = (__bf16)x.y; r[2] = (__bf16)x.z; r[3] = (__bf16)x.w;
    r[4] = (__bf16)y.x; r[5] = (__bf16)y.y; r[6] = (__bf16)y.z; r[7] = (__bf16)y.w;
    return r;
}

// 4 weight matrices (1024x1024 f32 -> bf16), grid (512,4).
__global__ __launch_bounds__(256) void cvt_w(
    const float* __restrict__ w0, const float* __restrict__ w1,
    const float* __restrict__ w2, const float* __restrict__ w3,
    __bf16* __restrict__ o0, __bf16* __restrict__ o1,
    __bf16* __restrict__ o2, __bf16* __restrict__ o3)
{
    const float* src; __bf16* dst;
    switch (blockIdx.y) {
        case 0: src = w0; dst = o0; break;
        case 1: src = w1; dst = o1; break;
        case 2: src = w2; dst = o2; break;
        default: src = w3; dst = o3; break;
    }
    size_t i = ((size_t)blockIdx.x * 256 + threadIdx.x) * 8;
    *reinterpret_cast<v8bf*>(dst + i) = cvt8(src + i);
}

// 3 activation inputs (4096x1024 f32 -> bf16), grid (2048,3).
__global__ __launch_bounds__(256) void cvt_in(
    const float* __restrict__ i0, const float* __restrict__ i1,
    const float* __restrict__ i2,
    __bf16* __restrict__ o0, __bf16* __restrict__ o1, __bf16* __restrict__ o2)
{
    const float* src; __bf16* dst;
    switch (blockIdx.y) {
        case 0: src = i0; dst = o0; break;
        case 1: src = i1; dst = o1; break;
        default: src = i2; dst = o2; break;
    }
    size_t i = ((size_t)blockIdx.x * 256 + threadIdx.x) * 8;
    *reinterpret_cast<v8bf*>(dst + i) = cvt8(src + i);
}

// Double-buffered DMA GEMM. Tile 128m x 64n, BK=64, 4 waves (wave: 64m x 32n).
// (unchanged, harness-verified)
__device__ __forceinline__ void gemm_body(
    const __bf16* __restrict__ A, const __bf16* __restrict__ W,
    const float* __restrict__ bias, void* __restrict__ outp,
    int mode, float oscale, int bx, int by)
{
    constexpr int K = 1024, N = 1024;
    __shared__ __align__(16) __bf16 As[2][128 * 64];
    __shared__ __align__(16) __bf16 Bs[2][64 * 64];

    const int lane = threadIdx.x & 63;
    const int wave = threadIdx.x >> 6;
    const int quad = lane >> 4;
    const int l15  = lane & 15;
    const int m_base = bx * 128;
    const int n_base = by * 64;
    const int wm = (wave & 1) * 64;
    const int wn = (wave >> 1) * 32;

    int arow[4], acol[4], brow[2], bcol[2];
    #pragma unroll
    for (int i = 0; i < 4; ++i) {
        int L = (i * 4 + wave) * 64 + lane;
        int r = L >> 3, s = L & 7;
        arow[i] = r; acol[i] = (s ^ (r & 7)) * 8;
    }
    #pragma unroll
    for (int i = 0; i < 2; ++i) {
        int L = (i * 4 + wave) * 64 + lane;
        int r = L >> 3, s = L & 7;
        brow[i] = r; bcol[i] = (s ^ (r & 7)) * 8;
    }

    v4f acc[4][2];
    #pragma unroll
    for (int f = 0; f < 4; ++f)
        #pragma unroll
        for (int g = 0; g < 2; ++g) { v4f z = {0.f,0.f,0.f,0.f}; acc[f][g] = z; }

    #pragma unroll
    for (int i = 0; i < 4; ++i)
        gl_lds16(A + (size_t)(m_base + arow[i]) * K + acol[i],
                 &As[0][(i * 4 + wave) * 512]);
    #pragma unroll
    for (int i = 0; i < 2; ++i)
        gl_lds16(W + (size_t)(n_base + brow[i]) * K + bcol[i],
                 &Bs[0][(i * 4 + wave) * 512]);
    __syncthreads();

    for (int it = 0; it < 16; ++it) {
        const int cur = it & 1, nxt = cur ^ 1;
        const int kn = ((it + 1) & 15) * 64;
        #pragma unroll
        for (int i = 0; i < 4; ++i)
            gl_lds16(A + (size_t)(m_base + arow[i]) * K + kn + acol[i],
                     &As[nxt][(i * 4 + wave) * 512]);
        #pragma unroll
        for (int i = 0; i < 2; ++i)
            gl_lds16(W + (size_t)(n_base + brow[i]) * K + kn + bcol[i],
                     &Bs[nxt][(i * 4 + wave) * 512]);

        #pragma unroll
        for (int ks = 0; ks < 2; ++ks) {
            v8bf af[4], bf[2];
            #pragma unroll
            for (int f = 0; f < 4; ++f) {
                const int R = wm + f * 16 + l15;
                const int slot = (ks * 4 + quad) ^ (R & 7);
                af[f] = *reinterpret_cast<const v8bf*>(&As[cur][R * 64 + slot * 8]);
            }
            #pragma unroll
            for (int g = 0; g < 2; ++g) {
                const int R = wn + g * 16 + l15;
                const int slot = (ks * 4 + quad) ^ (R & 7);
                bf[g] = *reinterpret_cast<const v8bf*>(&Bs[cur][R * 64 + slot * 8]);
            }
            __builtin_amdgcn_s_setprio(1);
            #pragma unroll
            for (int f = 0; f < 4; ++f)
                #pragma unroll
                for (int g = 0; g < 2; ++g)
                    acc[f][g] = __builtin_amdgcn_mfma_f32_16x16x32_bf16(
                        af[f], bf[g], acc[f][g], 0, 0, 0);
            __builtin_amdgcn_s_setprio(0);
        }
        __syncthreads();
    }

    #pragma unroll
    for (int f = 0; f < 4; ++f)
        #pragma unroll
        for (int g = 0; g < 2; ++g) {
            const int nc = n_base + wn + g * 16 + l15;
            const float bval = bias[nc];
            #pragma unroll
            for (int r = 0; r < 4; ++r) {
                const int m = m_base + wm + f * 16 + quad * 4 + r;
                const float v = (acc[f][g][r] + bval) * oscale;
                if (mode == 2) {
                    ((float*)outp)[(size_t)m * N + nc] = v;
                } else {
                    int b = m >> 11, n = m & 2047, h = nc >> 6, d = nc & 63;
                    size_t off = (mode == 0)
                        ? ((size_t)(b * 16 + h) * 2048 + n) * 64 + d
                        : ((size_t)(b * 16 + h) * 64 + d) * 2048 + n;
                    ((__bf16*)outp)[off] = (__bf16)v;
                }
            }
        }
}

// Fused QKV projections. 1D grid 1536: id%16 = by (by%8 -> XCD-local W slice).
__global__ __launch_bounds__(256) void qkv_gemm(
    const __bf16* __restrict__ Aq, const __bf16* __restrict__ Ak,
    const __bf16* __restrict__ Av,
    const __bf16* __restrict__ Wq, const __bf16* __restrict__ Wk,
    const __bf16* __restrict__ Wv,
    const float* __restrict__ bq, const float* __restrict__ bk,
    const float* __restrict__ bv,
    __bf16* __restrict__ Qo, __bf16* __restrict__ Ko, __bf16* __restrict__ Vo)
{
    const int id = blockIdx.x;
    const int by = id & 15;
    const int bx = (id >> 4) & 31;
    const int z  = id >> 9;

    const __bf16 *A, *W; const float* bias; __bf16* outp; float oscale; int mode;
    switch (z) {
        case 0:  A = Aq; W = Wq; bias = bq; outp = Qo; oscale = QSCALE; mode = 0; break;
        case 1:  A = Ak; W = Wk; bias = bk; outp = Ko; oscale = 1.0f;   mode = 0; break;
        default: A = Av; W = Wv; bias = bv; outp = Vo; oscale = 1.0f;   mode = 1; break;
    }
    gemm_body(A, W, bias, outp, mode, oscale, bx, by);
}

// Final projection, f32 out. 1D grid 512: id%16 = by.
__global__ __launch_bounds__(256) void out_gemm(
    const __bf16* __restrict__ A, const __bf16* __restrict__ W,
    const float* __restrict__ bias, float* __restrict__ outp)
{
    const int by = blockIdx.x & 15;
    const int bx = blockIdx.x >> 4;
    gemm_body(A, W, bias, outp, 2, 1.0f, bx, by);
}

// Flash attention, fixed-shift softmax, IN-REGISTER P (no P LDS round trip).
// Swapped QK^T at 32x32: St = mfma_32x32x16(A=K, B=Q) gives lane (q=lane&31)
// St.reg[r] = S[key = kb*32 + (r&3)+8*(r>>2)+4*(lane>>5)][q] -- the whole P
// row is lane-local, so the row-sum needs no cross-lane ops per kt, and P
// feeds PV's A-operand after cvt_pk + one permlane32_swap per register pair:
//   A-frag (32x32x16) lane needs keys 8*(lane>>5)+j; lane<32 owns {0-3},
//   lane+32 owns {4-7} -> swap(pk(r0,r1),pk(r4,r5)) fills both output words.
// K/V staging, triple-buffer + counted vmcnt kept from R4 (verified):
// 4 DMAs/lane/kt -> s_waitcnt vmcnt(4); Q loads drained (vmcnt(0)) before
// any DMA so the counted waits see only DMA ops.
// 4 waves x 32 q = 128 q/block. 1D grid 512: id%8 = bh%8 (XCD-local K/V).
// Q,K: bf16 [b,h,2048,64]; V: bf16 [b,h,64,2048]; O: bf16 [4096,1024].
__global__ __launch_bounds__(256, 2) void attn_kernel(
    const __bf16* __restrict__ Q, const __bf16* __restrict__ Kb_,
    const __bf16* __restrict__ Vt, __bf16* __restrict__ O)
{
    __shared__ __align__(16) __bf16 Ks[3][64 * 64];
    __shared__ __align__(16) __bf16 Vs[3][64 * 64];
    __shared__ float l_lds[4][32];

    const int lane = threadIdx.x & 63;
    const int wave = threadIdx.x >> 6;   // 0..3
    const int l31  = lane & 31;
    const int hi   = lane >> 5;          // 0/1
    const int bh = blockIdx.x & 31;      // id%8 = bh%8 -> XCD locality
    const int qt = blockIdx.x >> 5;      // 0..15 (128-row q tiles)
    const int b  = bh >> 4, h = bh & 15;

    const __bf16* Qh = Q   + (size_t)bh * 2048 * 64;
    const __bf16* Kh = Kb_ + (size_t)bh * 2048 * 64;
    const __bf16* Vh = Vt  + (size_t)bh * 64 * 2048;

    // Staging coords (verified 4-wave pattern): 2 DMA/lane for K, 2 for V.
    int srow[2], scol[2];
    #pragma unroll
    for (int i = 0; i < 2; ++i) {
        int L = (i * 4 + wave) * 64 + lane;
        int r = L >> 3, s = L & 7;
        srow[i] = r; scol[i] = (s ^ (r & 7)) * 8;
    }

    // Q fragments: B[n=q=l31][k_contract=d], d = t*16 + hi*8 + j.
    const int qrow = qt * 128 + wave * 32 + l31;
    v8bf qf[4];
    #pragma unroll
    for (int t = 0; t < 4; ++t)
        qf[t] = *reinterpret_cast<const v8bf*>(
            Qh + (size_t)qrow * 64 + t * 16 + hi * 8);
    // Drain Q loads so the in-loop counted vmcnt sees only DMA ops.
    asm volatile("s_waitcnt vmcnt(0)" ::: "memory");

    v16f o_acc[2];
    #pragma unroll
    for (int nt = 0; nt < 2; ++nt)
        #pragma unroll
        for (int r = 0; r < 16; ++r) o_acc[nt][r] = 0.f;
    float l_r = 0.f;

    // Prologue: kt=0 -> buf0, kt=1 -> buf1 (8 DMAs in flight).
    #pragma unroll
    for (int i = 0; i < 2; ++i) {
        gl_lds16(Kh + (size_t)srow[i] * 64 + scol[i], &Ks[0][(i * 4 + wave) * 512]);
        gl_lds16(Vh + (size_t)srow[i] * 2048 + scol[i], &Vs[0][(i * 4 + wave) * 512]);
    }
    #pragma unroll
    for (int i = 0; i < 2; ++i) {
        gl_lds16(Kh + (size_t)(64 + srow[i]) * 64 + scol[i], &Ks[1][(i * 4 + wave) * 512]);
        gl_lds16(Vh + (size_t)srow[i] * 2048 + 64 + scol[i], &Vs[1][(i * 4 + wave) * 512]);
    }
    asm volatile("s_waitcnt vmcnt(4)" ::: "memory");   // kt=0 landed
    __builtin_amdgcn_s_barrier();

    int cur = 0;
    for (int kt = 0; kt < 32; ++kt) {
        int pre = cur + 2; if (pre >= 3) pre -= 3;
        int ktn = kt + 2; if (ktn >= 32) ktn -= 32;   // wraps: wasted DMA, unread
        #pragma unroll
        for (int i = 0; i < 2; ++i) {
            gl_lds16(Kh + (size_t)(ktn * 64 + srow[i]) * 64 + scol[i],
                     &Ks[pre][(i * 4 + wave) * 512]);
            gl_lds16(Vh + (size_t)srow[i] * 2048 + ktn * 64 + scol[i],
                     &Vs[pre][(i * 4 + wave) * 512]);
        }

        // S^T = K @ Q^T per 32-key tile kb: St[kb].reg[r] =
        //   S[key = kb*32 + (r&3)+8*(r>>2)+4*hi][q = l31]
        v16f st[2];
        #pragma unroll
        for (int kb = 0; kb < 2; ++kb)
            #pragma unroll
            for (int r = 0; r < 16; ++r) st[kb][r] = 0.f;
        #pragma unroll
        for (int kb = 0; kb < 2; ++kb) {
            const int R = kb * 32 + l31;
            v8bf kf[4];
            #pragma unroll
            for (int t = 0; t < 4; ++t) {
                const int slot = (2 * t + hi) ^ (R & 7);
                kf[t] = *reinterpret_cast<const v8bf*>(&Ks[cur][R * 64 + slot * 8]);
            }
            __builtin_amdgcn_s_setprio(1);
            #pragma unroll
            for (int t = 0; t < 4; ++t)
                st[kb] = __builtin_amdgcn_mfma_f32_32x32x16_bf16(
                    kf[t], qf[t], st[kb], 0, 0, 0);
            __builtin_amdgcn_s_setprio(0);
        }

        // In-register softmax: p = 2^s, lane-local row-sum, pack+swap -> PV A.
        v8bf pa[2][2];   // [kb][s16]
        #pragma unroll
        for (int kb = 0; kb < 2; ++kb) {
            float p[16];
            #pragma unroll
            for (int r = 0; r < 16; ++r) p[r] = __builtin_exp2f(st[kb][r]);
            #pragma unroll
            for (int r = 0; r < 16; ++r) l_r += p[r];
            u32 w0 = cvtpk(p[0],  p[1]),  w1 = cvtpk(p[2],  p[3]);
            u32 w2 = cvtpk(p[4],  p[5]),  w3 = cvtpk(p[6],  p[7]);
            u32 w4 = cvtpk(p[8],  p[9]),  w5 = cvtpk(p[10], p[11]);
            u32 w6 = cvtpk(p[12], p[13]), w7 = cvtpk(p[14], p[15]);
            swapl(w0, w2); swapl(w1, w3);   // s16=0: keys 0-15 of tile
            swapl(w4, w6); swapl(w5, w7);   // s16=1: keys 16-31
            v4u t0; t0.x = w0; t0.y = w1; t0.z = w2; t0.w = w3;
            v4u t1; t1.x = w4; t1.y = w5; t1.z = w6; t1.w = w7;
            pa[kb][0] = __builtin_bit_cast(v8bf, t0);
            pa[kb][1] = __builtin_bit_cast(v8bf, t1);
        }

        // O^acc[nt].reg[r] = O[q=(r&3)+8*(r>>2)+4*hi][d = nt*32+l31]
        #pragma unroll
        for (int nt = 0; nt < 2; ++nt) {
            const int R = nt * 32 + l31;   // V^T row = d
            #pragma unroll
            for (int kb = 0; kb < 2; ++kb)
                #pragma unroll
                for (int s = 0; s < 2; ++s) {
                    const int slot = (kb * 4 + 2 * s + hi) ^ (R & 7);
                    v8bf vb = *reinterpret_cast<const v8bf*>(
                        &Vs[cur][R * 64 + slot * 8]);
                    __builtin_amdgcn_s_setprio(1);
                    o_acc[nt] = __builtin_amdgcn_mfma_f32_32x32x16_bf16(
                        pa[kb][s], vb, o_acc[nt], 0, 0, 0);
                    __builtin_amdgcn_s_setprio(0);
                }
        }

        // Counted wait: kt+1's 4 DMAs retired; kt+2's 4 stay in flight.
        asm volatile("s_waitcnt vmcnt(4)" ::: "memory");
        __builtin_amdgcn_s_barrier();
        cur = (cur == 2) ? 0 : cur + 1;
    }

    // l: lane holds half the keys for q=l31; pair-reduce with lane^32.
    float lt = l_r + __shfl_xor(l_r, 32);
    float inv = 1.0f / lt;
    if (lane < 32) l_lds[wave][l31] = inv;
    // O write: row q scattered over regs, col d = nt*32 + l31.
    #pragma unroll
    for (int nt = 0; nt < 2; ++nt)
        #pragma unroll
        for (int r = 0; r < 16; ++r) {
            const int qloc = (r & 3) + 8 * (r >> 2) + 4 * hi;
            const int q = qt * 128 + wave * 32 + qloc;
            const float v = o_acc[nt][r] * l_lds[wave][qloc];
            O[(size_t)(b * 2048 + q) * 1024 + h * 64 + nt * 32 + l31] = (__bf16)v;
        }
}

extern "C" void kernel_launch(void* const* d_in, const int* in_sizes, int n_in,
                              void* d_out, int out_size, void* d_ws, size_t ws_size,
                              hipStream_t stream) {
    const float* q_in = (const float*)d_in[0];
    const float* k_in = (const float*)d_in[1];
    const float* v_in = (const float*)d_in[2];
    const float* Wq = (const float*)d_in[3];
    const float* bq = (const float*)d_in[4];
    const float* Wk = (const float*)d_in[5];
    const float* bk = (const float*)d_in[6];
    const float* Wv = (const float*)d_in[7];
    const float* bv = (const float*)d_in[8];
    const float* Wo = (const float*)d_in[9];
    const float* bo = (const float*)d_in[10];
    float* out = (float*)d_out;

    // Workspace (bf16 elements), 56 MiB. Ob aliases Abq (consumed before attn).
    __bf16* ws  = (__bf16*)d_ws;
    __bf16* Abq = ws;                  // [4096,1024]
    __bf16* Abk = Abq + 4194304;
    __bf16* Abv = Abk + 4194304;
    __bf16* Qb  = Abv + 4194304;       // [2,16,2048,64]
    __bf16* Kb  = Qb  + 4194304;
    __bf16* Vb  = Kb  + 4194304;       // [2,16,64,2048]
    __bf16* Wqb = Vb  + 4194304;       // [1024,1024] x4
    __bf16* Wkb = Wqb + 1048576;
    __bf16* Wvb = Wkb + 1048576;
    __bf16* Wob = Wvb + 1048576;
    __bf16* Ob  = Abq;                 // alias

    cvt_w<<<dim3(512, 4), 256, 0, stream>>>(Wq, Wk, Wv, Wo, Wqb, Wkb, Wvb, Wob);
    cvt_in<<<dim3(2048, 3), 256, 0, stream>>>(q_in, k_in, v_in, Abq, Abk, Abv);

    qkv_gemm<<<1536, 256, 0, stream>>>(
        Abq, Abk, Abv, Wqb, Wkb, Wvb, bq, bk, bv, Qb, Kb, Vb);

    attn_kernel<<<512, 256, 0, stream>>>(Qb, Kb, Vb, Ob);

    out_gemm<<<512, 256, 0, stream>>>(Ob, Wob, bo, out);
}